// Round 8
// baseline (546.686 us; speedup 1.0000x reference)
//
#include <hip/hip_runtime.h>

typedef _Float16 half_t;
typedef __attribute__((ext_vector_type(8))) _Float16 half8;
typedef __attribute__((ext_vector_type(4))) _Float16 half4;
typedef __attribute__((ext_vector_type(4))) float float4_t;
typedef float f4u __attribute__((ext_vector_type(4), aligned(4)));  // 4B-aligned float4

#define BN_EPS 1e-5f

constexpr int Nn = 64, Cc = 64, Tt = 300, Vv = 25, Ss = 3;
constexpr int XA_S = 72;   // c-stride of wave-private xa rows (144 B: 16B-aligned, ~2-way banks)
constexpr int KCH  = 5;    // chunks per block; 4 timesteps/chunk -> 20 t per block; 300 = 15*20

// ---------------- precompute: fragment-major fp16 tables into workspace ----------------
// aeh[s][wt][lane][8] : Ae^T fragment  B[k=v][n=w], v=(lane>>4)*8+j, w=wt*16+(lane&15), zero-padded
// wch[s][ot][ks][lane][8] : Wc fragment A[m=o][k=c], o=ot*16+(lane&15), c=ks*32+(lane>>4)*8+j
// bnsc/bnsh[64] : BN scale/shift with sum_s bc folded in
__global__ __launch_bounds__(256, 1)
void gcn_pre(const float* __restrict__ A,   const float* __restrict__ PA1,
             const float* __restrict__ PA2, const float* __restrict__ Wc,
             const float* __restrict__ bc,  const float* __restrict__ gamma,
             const float* __restrict__ beta, const float* __restrict__ rmean,
             const float* __restrict__ rvar,
             half_t* __restrict__ aeh, half_t* __restrict__ wch,
             float* __restrict__ bnsc, float* __restrict__ bnsh)
{
    const int tid = threadIdx.x;
    if (tid < Cc) {
        float sc   = gamma[tid] * rsqrtf(rvar[tid] + BN_EPS);
        float bsum = bc[tid] + bc[Cc + tid] + bc[2 * Cc + tid];
        bnsc[tid] = sc;
        bnsh[tid] = beta[tid] - rmean[tid] * sc + bsum * sc;
    }
    for (int e = tid; e < Ss * 2 * 64; e += 256) {        // AeT fragments
        int s = e >> 7, wt = (e >> 6) & 1, lane = e & 63;
        int col = lane & 15, q = lane >> 4;
        int w = wt * 16 + col;
        #pragma unroll
        for (int j = 0; j < 8; ++j) {
            int v = q * 8 + j;
            float val = 0.f;
            if (v < Vv && w < Vv) {
                int ai = (s * Vv + v) * Vv + w;
                val = A[ai] * PA1[ai] + PA2[ai];
            }
            aeh[e * 8 + j] = (half_t)val;
        }
    }
    for (int e = tid; e < Ss * 4 * 2 * 64; e += 256) {    // Wc fragments
        int s = e >> 9, r = e & 511, ot = r >> 7, ks = (r >> 6) & 1, lane = r & 63;
        int col = lane & 15, q = lane >> 4;
        int o = ot * 16 + col;
        #pragma unroll
        for (int j = 0; j < 8; ++j) {
            int c = ks * 32 + q * 8 + j;
            wch[e * 8 + j] = (half_t)Wc[(s * Cc + o) * Cc + c];
        }
    }
}

// ---- main: R3 body verbatim, made persistent over 5 chunks; barrier-free, 4 blocks/CU ----
__global__ __launch_bounds__(256, 4)
void gcn_main(const float* __restrict__ x, const half_t* __restrict__ aeh,
              const half_t* __restrict__ wch, const float* __restrict__ bnsc,
              const float* __restrict__ bnsh, float* __restrict__ out)
{
    // wave-private xa transpose scratch: [wave][w 0..31][c 0..63 +pad] = 18432 B
    __shared__ __align__(16) half_t xaW[4][32][XA_S];

    const int tid  = threadIdx.x;
    const int lane = tid & 63;
    const int wave = tid >> 6;      // 0..3 -> owns timestep (chunk*4 + wave)
    const int col  = lane & 15;
    const int quad = lane >> 4;

    const int n     = blockIdx.y;
    const int tbase = blockIdx.x * (4 * KCH);   // 20-timestep span, exact (300 = 15*20)

    // ---- Ae^T B-fragments, all s, loaded ONCE per block (amortized 5x vs R3) ----
    half8 ab[Ss][2];
    #pragma unroll
    for (int s = 0; s < Ss; ++s)
        #pragma unroll
        for (int wt = 0; wt < 2; ++wt)
            ab[s][wt] = *(const half8*)&aeh[((s * 2 + wt) * 64 + lane) * 8];

    const float4_t zero4 = {0.f, 0.f, 0.f, 0.f};

    for (int k = 0; k < KCH; ++k) {
        const int tg = tbase + k * 4 + wave;

        // ---- x A-fragments direct from global: af[ct] = x[c=ct*16+col][tg][v=quad*8+j] ----
        half8 af[4];
        #pragma unroll
        for (int ct = 0; ct < 4; ++ct) {
            const float* p = x + ((size_t)(n * Cc + ct * 16 + col) * Tt + tg) * Vv;
            half8 h;
            if (quad < 3) {
                f4u a0 = *(const f4u*)(p + quad * 8);      // rows 100B-strided: 4B-aligned
                f4u a1 = *(const f4u*)(p + quad * 8 + 4);
                #pragma unroll
                for (int j = 0; j < 4; ++j) { h[j] = (half_t)a0[j]; h[4 + j] = (half_t)a1[j]; }
            } else {
                h[0] = (half_t)p[24];                      // v=24; v=25..31 are K-pad zeros
                #pragma unroll
                for (int j = 1; j < 8; ++j) h[j] = (half_t)0.f;
            }
            af[ct] = h;
        }

        float4_t yacc[4][2];
        #pragma unroll
        for (int ot = 0; ot < 4; ++ot)
            #pragma unroll
            for (int wt = 0; wt < 2; ++wt) yacc[ot][wt] = zero4;

        #pragma unroll
        for (int s = 0; s < Ss; ++s) {
            // ---- stage 1: xa[c][w] = x · Ae[s] for this wave's t (8 MFMA) ----
            // D[m=c=ct*16+quad*4+i][n=w=wt*16+col]; Ae cols w>=25 are zero -> rows 25..31 = 0
            #pragma unroll
            for (int ct = 0; ct < 4; ++ct)
                #pragma unroll
                for (int wt = 0; wt < 2; ++wt) {
                    float4_t r = __builtin_amdgcn_mfma_f32_16x16x32_f16(af[ct], ab[s][wt], zero4, 0, 0, 0);
                    half4 h;
                    #pragma unroll
                    for (int i = 0; i < 4; ++i) h[i] = (half_t)r[i];
                    *(half4*)&xaW[wave][wt * 16 + col][ct * 16 + quad * 4] = h;
                }
            // ---- same-wave transpose readback: B[k=c=ks*32+quad*8+j][n=w=wt*16+col] ----
            // (write->read same wave: lgkmcnt ordering, NO barrier)
            half8 bf[2][2];
            #pragma unroll
            for (int ks = 0; ks < 2; ++ks)
                #pragma unroll
                for (int wt = 0; wt < 2; ++wt)
                    bf[ks][wt] = *(const half8*)&xaW[wave][wt * 16 + col][ks * 32 + quad * 8];
            // ---- stage 2: y[o][w] += Wc[s] · xa  (16 MFMA), wch streamed from L1/L2 table ----
            #pragma unroll
            for (int ot = 0; ot < 4; ++ot) {
                half8 w0 = *(const half8*)&wch[(((s * 4 + ot) * 2 + 0) * 64 + lane) * 8];
                half8 w1 = *(const half8*)&wch[(((s * 4 + ot) * 2 + 1) * 64 + lane) * 8];
                #pragma unroll
                for (int wt = 0; wt < 2; ++wt) {
                    yacc[ot][wt] = __builtin_amdgcn_mfma_f32_16x16x32_f16(w0, bf[0][wt], yacc[ot][wt], 0, 0, 0);
                    yacc[ot][wt] = __builtin_amdgcn_mfma_f32_16x16x32_f16(w1, bf[1][wt], yacc[ot][wt], 0, 0, 0);
                }
            }
        }

        // ---- epilogue: BN + residual (x re-read, L1-hot from af gather) + ReLU ----
        const size_t base = (size_t)n * Cc * Tt * Vv + (size_t)tg * Vv;
        const float* xr   = x + base;
        float* outr       = out + base;
        #pragma unroll
        for (int ot = 0; ot < 4; ++ot) {
            float4_t sc = *(const float4_t*)&bnsc[ot * 16 + quad * 4];   // 16B-aligned, hot
            float4_t sh = *(const float4_t*)&bnsh[ot * 16 + quad * 4];
            #pragma unroll
            for (int i = 0; i < 4; ++i) {
                const int ro = (ot * 16 + quad * 4 + i) * (Tt * Vv);     // 32-bit offset math
                #pragma unroll
                for (int wt = 0; wt < 2; ++wt) {
                    int w = wt * 16 + col;
                    if (w < Vv) {
                        float val = yacc[ot][wt][i] * sc[i] + sh[i] + xr[ro + w];
                        outr[ro + w] = fmaxf(val, 0.f);
                    }
                }
            }
        }
        // no barrier: xaW is wave-private, next chunk's writes are same-wave ordered
    }
}

extern "C" void kernel_launch(void* const* d_in, const int* in_sizes, int n_in,
                              void* d_out, int out_size, void* d_ws, size_t ws_size,
                              hipStream_t stream) {
    const float* x     = (const float*)d_in[0];
    const float* A     = (const float*)d_in[1];
    const float* PA1   = (const float*)d_in[2];
    const float* PA2   = (const float*)d_in[3];
    const float* Wc    = (const float*)d_in[4];
    const float* bc    = (const float*)d_in[5];
    const float* gamma = (const float*)d_in[6];
    const float* beta  = (const float*)d_in[7];
    const float* rmean = (const float*)d_in[8];
    const float* rvar  = (const float*)d_in[9];
    float* out = (float*)d_out;

    // workspace layout (37,376 B): aeh | wch | bnsc | bnsh
    half_t* aeh = (half_t*)d_ws;                      // 3*2*64*8  = 3072 halfs
    half_t* wch = aeh + Ss * 2 * 64 * 8;              // 3*4*2*64*8 = 12288 halfs
    float* bnsc = (float*)(wch + Ss * 4 * 2 * 64 * 8);
    float* bnsh = bnsc + Cc;

    gcn_pre<<<dim3(1), 256, 0, stream>>>(A, PA1, PA2, Wc, bc, gamma, beta, rmean, rvar,
                                         aeh, wch, bnsc, bnsh);
    // (15, 64) = 960 blocks, all co-resident at 4 blocks/CU: ONE dispatch, no re-dispatch
    // phase-locking; blocks desynchronize across chunks -> smoothed HBM demand
    gcn_main<<<dim3(Tt / (4 * KCH), Nn), 256, 0, stream>>>(x, aeh, wch, bnsc, bnsh, out);
}

// Round 9
// 329.568 us; speedup vs baseline: 1.6588x; 1.6588x over previous
//
#include <hip/hip_runtime.h>

typedef _Float16 half_t;
typedef __attribute__((ext_vector_type(8))) _Float16 half8;
typedef __attribute__((ext_vector_type(4))) _Float16 half4;
typedef __attribute__((ext_vector_type(4))) float float4_t;
typedef float f4u __attribute__((ext_vector_type(4), aligned(4)));  // 4B-aligned float4

#define BN_EPS 1e-5f

constexpr int Nn = 64, Cc = 64, Tt = 300, Vv = 25, Ss = 3;
constexpr int XA_S = 72;   // c-stride of wave-private xa rows (144 B: 16B-aligned, ~2-way banks)
constexpr int TC   = 12;   // t-slab per transpose block; 300 = 25*12

// ---------------- precompute: fragment-major fp16 tables into workspace ----------------
__global__ __launch_bounds__(256, 1)
void gcn_pre(const float* __restrict__ A,   const float* __restrict__ PA1,
             const float* __restrict__ PA2, const float* __restrict__ Wc,
             const float* __restrict__ bc,  const float* __restrict__ gamma,
             const float* __restrict__ beta, const float* __restrict__ rmean,
             const float* __restrict__ rvar,
             half_t* __restrict__ aeh, half_t* __restrict__ wch,
             float* __restrict__ bnsc, float* __restrict__ bnsh)
{
    const int tid = threadIdx.x;
    if (tid < Cc) {
        float sc   = gamma[tid] * rsqrtf(rvar[tid] + BN_EPS);
        float bsum = bc[tid] + bc[Cc + tid] + bc[2 * Cc + tid];
        bnsc[tid] = sc;
        bnsh[tid] = beta[tid] - rmean[tid] * sc + bsum * sc;
    }
    for (int e = tid; e < Ss * 2 * 64; e += 256) {        // AeT fragments
        int s = e >> 7, wt = (e >> 6) & 1, lane = e & 63;
        int col = lane & 15, q = lane >> 4;
        int w = wt * 16 + col;
        #pragma unroll
        for (int j = 0; j < 8; ++j) {
            int v = q * 8 + j;
            float val = 0.f;
            if (v < Vv && w < Vv) {
                int ai = (s * Vv + v) * Vv + w;
                val = A[ai] * PA1[ai] + PA2[ai];
            }
            aeh[e * 8 + j] = (half_t)val;
        }
    }
    for (int e = tid; e < Ss * 4 * 2 * 64; e += 256) {    // Wc fragments
        int s = e >> 9, r = e & 511, ot = r >> 7, ks = (r >> 6) & 1, lane = r & 63;
        int col = lane & 15, q = lane >> 4;
        int o = ot * 16 + col;
        #pragma unroll
        for (int j = 0; j < 8; ++j) {
            int c = ks * 32 + q * 8 + j;
            wch[e * 8 + j] = (half_t)Wc[(s * Cc + o) * Cc + c];
        }
    }
}

// ---- streaming transpose: x (fp32, NCTV) -> xh (fp16, [n][t][c][v32], v>=25 zeroed) ----
// reads: 1.2 KB contiguous granules per c-row; writes: 48 KB contiguous per block.
__global__ __launch_bounds__(256, 3)
void gcn_tr(const float* __restrict__ x, half_t* __restrict__ xh)
{
    __shared__ half_t xt[TC][Cc][32];    // 49152 B -> 3 blocks/CU
    const int tid = threadIdx.x;
    const int n  = blockIdx.y;
    const int t0 = blockIdx.x * TC;
    const float* xb = x + (size_t)n * Cc * Tt * Vv + t0 * Vv;

    // zero the v-pads
    for (int i = tid; i < TC * Cc * 7; i += 256) {
        int t = i / (Cc * 7), r = i % (Cc * 7), c = r / 7, j = r % 7;
        xt[t][c][25 + j] = (half_t)0.f;
    }
    // streaming read: 64 c-rows x 300 floats (75 float4, 16B-aligned: t0*25*4 = bx*1200)
    for (int i = tid; i < Cc * 75; i += 256) {
        int c = i / 75, q = i - c * 75;
        float4_t f = *(const float4_t*)(xb + c * (Tt * Vv) + q * 4);
        #pragma unroll
        for (int j = 0; j < 4; ++j) {
            int g = q * 4 + j;           // 0..299 within the slab
            int t = g / 25, v = g - t * 25;
            xt[t][c][v] = (half_t)f[j];
        }
    }
    __syncthreads();
    // streaming write: [t][c][v32] contiguous, 16B per thread-op
    half_t* dst = xh + ((size_t)n * Tt + t0) * (Cc * 32);
    for (int i = tid; i < TC * Cc * 4; i += 256) {
        int t = i >> 8, r = i & 255, c = r >> 2, k = r & 3;
        *(half8*)(dst + (t * Cc + c) * 32 + k * 8) = *(const half8*)&xt[t][c][k * 8];
    }
}

// ---- main: R3 structure verbatim; af + residual from fp16 t-major xh (16KB/block stream) ----
__global__ __launch_bounds__(256, 4)
void gcn_main(const half_t* __restrict__ xh, const half_t* __restrict__ aeh,
              const half_t* __restrict__ wch, const float* __restrict__ bnsc,
              const float* __restrict__ bnsh, float* __restrict__ out)
{
    // wave-private xa transpose scratch: [wave][w 0..31][c 0..63 +pad] = 18432 B
    __shared__ __align__(16) half_t xaW[4][32][XA_S];

    const int tid  = threadIdx.x;
    const int lane = tid & 63;
    const int wave = tid >> 6;      // 0..3 -> owns timestep tg
    const int col  = lane & 15;
    const int quad = lane >> 4;

    const int n  = blockIdx.y;
    const int tg = blockIdx.x * 4 + wave;     // 0..299 exact

    // ---- Ae^T B-fragments, all s (L1/L2-hot table) ----
    half8 ab[Ss][2];
    #pragma unroll
    for (int s = 0; s < Ss; ++s)
        #pragma unroll
        for (int wt = 0; wt < 2; ++wt)
            ab[s][wt] = *(const half8*)&aeh[((s * 2 + wt) * 64 + lane) * 8];

    // ---- x A-fragments: one contiguous 4KB slab per wave (16B/lane x 4, no cvt, no branch) ----
    const half_t* slab = xh + ((size_t)n * Tt + tg) * (Cc * 32);
    half8 af[4];
    #pragma unroll
    for (int ct = 0; ct < 4; ++ct)
        af[ct] = *(const half8*)(slab + (ct * 16 + col) * 32 + quad * 8);

    const float4_t zero4 = {0.f, 0.f, 0.f, 0.f};
    float4_t yacc[4][2];
    #pragma unroll
    for (int ot = 0; ot < 4; ++ot)
        #pragma unroll
        for (int wt = 0; wt < 2; ++wt) yacc[ot][wt] = zero4;

    #pragma unroll
    for (int s = 0; s < Ss; ++s) {
        // ---- stage 1: xa[c][w] = x · Ae[s] for this wave's t (8 MFMA) ----
        #pragma unroll
        for (int ct = 0; ct < 4; ++ct)
            #pragma unroll
            for (int wt = 0; wt < 2; ++wt) {
                float4_t r = __builtin_amdgcn_mfma_f32_16x16x32_f16(af[ct], ab[s][wt], zero4, 0, 0, 0);
                half4 h;
                #pragma unroll
                for (int i = 0; i < 4; ++i) h[i] = (half_t)r[i];
                *(half4*)&xaW[wave][wt * 16 + col][ct * 16 + quad * 4] = h;
            }
        // ---- same-wave transpose readback (lgkmcnt-ordered, NO barrier) ----
        half8 bf[2][2];
        #pragma unroll
        for (int ks = 0; ks < 2; ++ks)
            #pragma unroll
            for (int wt = 0; wt < 2; ++wt)
                bf[ks][wt] = *(const half8*)&xaW[wave][wt * 16 + col][ks * 32 + quad * 8];
        // ---- stage 2: y[o][w] += Wc[s] · xa  (16 MFMA), wch streamed from L1/L2 table ----
        #pragma unroll
        for (int ot = 0; ot < 4; ++ot) {
            half8 w0 = *(const half8*)&wch[(((s * 4 + ot) * 2 + 0) * 64 + lane) * 8];
            half8 w1 = *(const half8*)&wch[(((s * 4 + ot) * 2 + 1) * 64 + lane) * 8];
            #pragma unroll
            for (int wt = 0; wt < 2; ++wt) {
                yacc[ot][wt] = __builtin_amdgcn_mfma_f32_16x16x32_f16(w0, bf[0][wt], yacc[ot][wt], 0, 0, 0);
                yacc[ot][wt] = __builtin_amdgcn_mfma_f32_16x16x32_f16(w1, bf[1][wt], yacc[ot][wt], 0, 0, 0);
            }
        }
    }

    // ---- epilogue: BN + residual (fp16 slab re-read, L1-hot) + ReLU ----
    float* outr = out + ((size_t)n * Cc * Tt + tg) * Vv;
    #pragma unroll
    for (int ot = 0; ot < 4; ++ot) {
        float4_t sc = *(const float4_t*)&bnsc[ot * 16 + quad * 4];   // 16B-aligned, hot
        float4_t sh = *(const float4_t*)&bnsh[ot * 16 + quad * 4];
        #pragma unroll
        for (int i = 0; i < 4; ++i) {
            const int o  = ot * 16 + quad * 4 + i;
            const int ro = o * (Tt * Vv);
            #pragma unroll
            for (int wt = 0; wt < 2; ++wt) {
                int w = wt * 16 + col;
                if (w < Vv) {
                    float val = yacc[ot][wt][i] * sc[i] + sh[i] + (float)slab[o * 32 + w];
                    outr[ro + w] = fmaxf(val, 0.f);
                }
            }
        }
    }
}

// ---- fallback main (exact R3): used only if ws_size can't hold xh ----
__global__ __launch_bounds__(256, 4)
void gcn_main_fb(const float* __restrict__ x, const half_t* __restrict__ aeh,
                 const half_t* __restrict__ wch, const float* __restrict__ bnsc,
                 const float* __restrict__ bnsh, float* __restrict__ out)
{
    __shared__ __align__(16) half_t xaW[4][32][XA_S];
    const int tid  = threadIdx.x;
    const int lane = tid & 63;
    const int wave = tid >> 6;
    const int col  = lane & 15;
    const int quad = lane >> 4;
    const int n  = blockIdx.y;
    const int tg = blockIdx.x * 4 + wave;

    half8 ab[Ss][2];
    #pragma unroll
    for (int s = 0; s < Ss; ++s)
        #pragma unroll
        for (int wt = 0; wt < 2; ++wt)
            ab[s][wt] = *(const half8*)&aeh[((s * 2 + wt) * 64 + lane) * 8];

    half8 af[4];
    #pragma unroll
    for (int ct = 0; ct < 4; ++ct) {
        const float* p = x + ((size_t)(n * Cc + ct * 16 + col) * Tt + tg) * Vv;
        half8 h;
        if (quad < 3) {
            f4u a0 = *(const f4u*)(p + quad * 8);
            f4u a1 = *(const f4u*)(p + quad * 8 + 4);
            #pragma unroll
            for (int j = 0; j < 4; ++j) { h[j] = (half_t)a0[j]; h[4 + j] = (half_t)a1[j]; }
        } else {
            h[0] = (half_t)p[24];
            #pragma unroll
            for (int j = 1; j < 8; ++j) h[j] = (half_t)0.f;
        }
        af[ct] = h;
    }

    const float4_t zero4 = {0.f, 0.f, 0.f, 0.f};
    float4_t yacc[4][2];
    #pragma unroll
    for (int ot = 0; ot < 4; ++ot)
        #pragma unroll
        for (int wt = 0; wt < 2; ++wt) yacc[ot][wt] = zero4;

    #pragma unroll
    for (int s = 0; s < Ss; ++s) {
        #pragma unroll
        for (int ct = 0; ct < 4; ++ct)
            #pragma unroll
            for (int wt = 0; wt < 2; ++wt) {
                float4_t r = __builtin_amdgcn_mfma_f32_16x16x32_f16(af[ct], ab[s][wt], zero4, 0, 0, 0);
                half4 h;
                #pragma unroll
                for (int i = 0; i < 4; ++i) h[i] = (half_t)r[i];
                *(half4*)&xaW[wave][wt * 16 + col][ct * 16 + quad * 4] = h;
            }
        half8 bf[2][2];
        #pragma unroll
        for (int ks = 0; ks < 2; ++ks)
            #pragma unroll
            for (int wt = 0; wt < 2; ++wt)
                bf[ks][wt] = *(const half8*)&xaW[wave][wt * 16 + col][ks * 32 + quad * 8];
        #pragma unroll
        for (int ot = 0; ot < 4; ++ot) {
            half8 w0 = *(const half8*)&wch[(((s * 4 + ot) * 2 + 0) * 64 + lane) * 8];
            half8 w1 = *(const half8*)&wch[(((s * 4 + ot) * 2 + 1) * 64 + lane) * 8];
            #pragma unroll
            for (int wt = 0; wt < 2; ++wt) {
                yacc[ot][wt] = __builtin_amdgcn_mfma_f32_16x16x32_f16(w0, bf[0][wt], yacc[ot][wt], 0, 0, 0);
                yacc[ot][wt] = __builtin_amdgcn_mfma_f32_16x16x32_f16(w1, bf[1][wt], yacc[ot][wt], 0, 0, 0);
            }
        }
    }

    const size_t base = (size_t)n * Cc * Tt * Vv + (size_t)tg * Vv;
    const float* xr   = x + base;
    float* outr       = out + base;
    #pragma unroll
    for (int ot = 0; ot < 4; ++ot) {
        float4_t sc = *(const float4_t*)&bnsc[ot * 16 + quad * 4];
        float4_t sh = *(const float4_t*)&bnsh[ot * 16 + quad * 4];
        #pragma unroll
        for (int i = 0; i < 4; ++i) {
            const int ro = (ot * 16 + quad * 4 + i) * (Tt * Vv);
            #pragma unroll
            for (int wt = 0; wt < 2; ++wt) {
                int w = wt * 16 + col;
                if (w < Vv) {
                    float val = yacc[ot][wt][i] * sc[i] + sh[i] + xr[ro + w];
                    outr[ro + w] = fmaxf(val, 0.f);
                }
            }
        }
    }
}

extern "C" void kernel_launch(void* const* d_in, const int* in_sizes, int n_in,
                              void* d_out, int out_size, void* d_ws, size_t ws_size,
                              hipStream_t stream) {
    const float* x     = (const float*)d_in[0];
    const float* A     = (const float*)d_in[1];
    const float* PA1   = (const float*)d_in[2];
    const float* PA2   = (const float*)d_in[3];
    const float* Wc    = (const float*)d_in[4];
    const float* bc    = (const float*)d_in[5];
    const float* gamma = (const float*)d_in[6];
    const float* beta  = (const float*)d_in[7];
    const float* rmean = (const float*)d_in[8];
    const float* rvar  = (const float*)d_in[9];
    float* out = (float*)d_out;

    // workspace layout: aeh(6144B) | wch(24576B) | bnsc(256B) | bnsh(256B) | xh(75MB)
    half_t* aeh = (half_t*)d_ws;                      // 3*2*64*8  = 3072 halfs
    half_t* wch = aeh + Ss * 2 * 64 * 8;              // 3*4*2*64*8 = 12288 halfs
    float* bnsc = (float*)(wch + Ss * 4 * 2 * 64 * 8);
    float* bnsh = bnsc + Cc;
    half_t* xh  = (half_t*)((char*)d_ws + 31232);     // 256-aligned
    const size_t XH_BYTES = (size_t)Nn * Tt * Cc * 32 * sizeof(half_t);  // 78,643,200

    gcn_pre<<<dim3(1), 256, 0, stream>>>(A, PA1, PA2, Wc, bc, gamma, beta, rmean, rvar,
                                         aeh, wch, bnsc, bnsh);
    if (ws_size >= 31232 + XH_BYTES) {
        gcn_tr<<<dim3(Tt / TC, Nn), 256, 0, stream>>>(x, xh);          // (25, 64)
        gcn_main<<<dim3(Tt / 4, Nn), 256, 0, stream>>>(xh, aeh, wch, bnsc, bnsh, out);
    } else {
        gcn_main_fb<<<dim3(Tt / 4, Nn), 256, 0, stream>>>(x, aeh, wch, bnsc, bnsh, out);
    }
}

// Round 10
// 287.998 us; speedup vs baseline: 1.8982x; 1.1443x over previous
//
#include <hip/hip_runtime.h>

typedef _Float16 half_t;
typedef __attribute__((ext_vector_type(8))) _Float16 half8;
typedef __attribute__((ext_vector_type(4))) _Float16 half4;
typedef __attribute__((ext_vector_type(4))) float float4_t;

#define BN_EPS 1e-5f

constexpr int Nn = 64, Cc = 64, Tt = 300, Vv = 25, Ss = 3;
constexpr int XA_S = 72;   // c-stride of wave-private xa rows (144 B: 16B-aligned, ~2-way banks)

// ---------------- precompute: fragment-major fp16 tables into workspace ----------------
// aeh[s][wt][lane][8] : Ae^T fragment  B[k=v][n=w], v=(lane>>4)*8+j, w=wt*16+(lane&15), zero-padded
// wch[s][ot][ks][lane][8] : Wc fragment A[m=o][k=c], o=ot*16+(lane&15), c=ks*32+(lane>>4)*8+j
__global__ __launch_bounds__(256, 1)
void gcn_pre(const float* __restrict__ A,   const float* __restrict__ PA1,
             const float* __restrict__ PA2, const float* __restrict__ Wc,
             const float* __restrict__ bc,  const float* __restrict__ gamma,
             const float* __restrict__ beta, const float* __restrict__ rmean,
             const float* __restrict__ rvar,
             half_t* __restrict__ aeh, half_t* __restrict__ wch,
             float* __restrict__ bnsc, float* __restrict__ bnsh)
{
    const int tid = threadIdx.x;
    if (tid < Cc) {
        float sc   = gamma[tid] * rsqrtf(rvar[tid] + BN_EPS);
        float bsum = bc[tid] + bc[Cc + tid] + bc[2 * Cc + tid];
        bnsc[tid] = sc;
        bnsh[tid] = beta[tid] - rmean[tid] * sc + bsum * sc;
    }
    for (int e = tid; e < Ss * 2 * 64; e += 256) {        // AeT fragments
        int s = e >> 7, wt = (e >> 6) & 1, lane = e & 63;
        int col = lane & 15, q = lane >> 4;
        int w = wt * 16 + col;
        #pragma unroll
        for (int j = 0; j < 8; ++j) {
            int v = q * 8 + j;
            float val = 0.f;
            if (v < Vv && w < Vv) {
                int ai = (s * Vv + v) * Vv + w;
                val = A[ai] * PA1[ai] + PA2[ai];
            }
            aeh[e * 8 + j] = (half_t)val;
        }
    }
    for (int e = tid; e < Ss * 4 * 2 * 64; e += 256) {    // Wc fragments
        int s = e >> 9, r = e & 511, ot = r >> 7, ks = (r >> 6) & 1, lane = r & 63;
        int col = lane & 15, q = lane >> 4;
        int o = ot * 16 + col;
        #pragma unroll
        for (int j = 0; j < 8; ++j) {
            int c = ks * 32 + q * 8 + j;
            wch[e * 8 + j] = (half_t)Wc[(s * Cc + o) * Cc + c];
        }
    }
}

// ---- fused main: DMA-staged x in LDS, barrier-free s-loop, LDS-staged coalesced out ----
__global__ __launch_bounds__(256, 3)
void gcn_fused(const float* __restrict__ x, const half_t* __restrict__ aeh,
               const half_t* __restrict__ wch, const float* __restrict__ bnsc,
               const float* __restrict__ bnsh, float* __restrict__ out)
{
    // x slab for this (n, 4-timestep) block, raw fp32 [c][t*25+v] = 25600 B.
    // After the s-loop it is updated IN PLACE to the output values and flushed.
    __shared__ __align__(16) float xs[Cc * 100];
    // wave-private xa transpose scratch: [wave][w 0..31][c 0..63 +pad] = 18432 B
    __shared__ __align__(16) half_t xaW[4][32][XA_S];
    // total 44032 B -> 3 blocks/CU

    const int tid  = threadIdx.x;
    const int lane = tid & 63;
    const int wave = tid >> 6;      // 0..3 -> owns timestep t0+wave
    const int col  = lane & 15;
    const int quad = lane >> 4;

    const int n  = blockIdx.y;
    const int t0 = blockIdx.x * 4;                    // 0..296, exact (300/4 = 75)
    const float* xb = x + (size_t)n * Cc * Tt * Vv + t0 * Vv;

    // ---- stage x: 1600 float4 via global_load_lds (400 B granules per c-row, 0 reg cost) ----
    for (int i = tid; i < 1600; i += 256) {
        int c = i / 25, q = i - c * 25;               // q = float4 index within 100-float row
        const float* g = xb + c * (Tt * Vv) + q * 4;  // 16B-aligned (t0*100 B, c*30000 B)
        __builtin_amdgcn_global_load_lds(
            (const __attribute__((address_space(1))) unsigned int*)g,
            (__attribute__((address_space(3))) unsigned int*)&xs[i * 4],
            16, 0, 0);
    }

    // ---- Ae^T B-fragments, all s (L1/L2-hot table) — overlaps the DMA ----
    half8 ab[Ss][2];
    #pragma unroll
    for (int s = 0; s < Ss; ++s)
        #pragma unroll
        for (int wt = 0; wt < 2; ++wt)
            ab[s][wt] = *(const half8*)&aeh[((s * 2 + wt) * 64 + lane) * 8];

    __syncthreads();   // DMA drained (vmcnt0) + visible to all waves

    // ---- af fragments from LDS slab: af[ct] = x[c=ct*16+col][t=wave][v=quad*8+j] ----
    half8 af[4];
    #pragma unroll
    for (int ct = 0; ct < 4; ++ct) {
        const float* r = &xs[(ct * 16 + col) * 100 + wave * 25];
        half8 h;
        if (quad < 3) {
            #pragma unroll
            for (int j = 0; j < 8; ++j) h[j] = (half_t)r[quad * 8 + j];
        } else {
            h[0] = (half_t)r[24];                     // v=24; v=25..31 are K-pad zeros
            #pragma unroll
            for (int j = 1; j < 8; ++j) h[j] = (half_t)0.f;
        }
        af[ct] = h;
    }

    const float4_t zero4 = {0.f, 0.f, 0.f, 0.f};
    float4_t yacc[4][2];
    #pragma unroll
    for (int ot = 0; ot < 4; ++ot)
        #pragma unroll
        for (int wt = 0; wt < 2; ++wt) yacc[ot][wt] = zero4;

    #pragma unroll
    for (int s = 0; s < Ss; ++s) {
        // ---- stage 1: xa[c][w] = x · Ae[s] for this wave's t (8 MFMA) ----
        // D[m=c=ct*16+quad*4+i][n=w=wt*16+col]; Ae cols w>=25 are zero -> rows 25..31 = 0
        #pragma unroll
        for (int ct = 0; ct < 4; ++ct)
            #pragma unroll
            for (int wt = 0; wt < 2; ++wt) {
                float4_t r = __builtin_amdgcn_mfma_f32_16x16x32_f16(af[ct], ab[s][wt], zero4, 0, 0, 0);
                half4 h;
                #pragma unroll
                for (int i = 0; i < 4; ++i) h[i] = (half_t)r[i];
                *(half4*)&xaW[wave][wt * 16 + col][ct * 16 + quad * 4] = h;
            }
        // ---- same-wave transpose readback (lgkmcnt-ordered, NO barrier) ----
        half8 bf[2][2];
        #pragma unroll
        for (int ks = 0; ks < 2; ++ks)
            #pragma unroll
            for (int wt = 0; wt < 2; ++wt)
                bf[ks][wt] = *(const half8*)&xaW[wave][wt * 16 + col][ks * 32 + quad * 8];
        // ---- stage 2: y[o][w] += Wc[s] · xa  (16 MFMA), wch streamed from L1/L2 table ----
        #pragma unroll
        for (int ot = 0; ot < 4; ++ot) {
            half8 w0 = *(const half8*)&wch[(((s * 4 + ot) * 2 + 0) * 64 + lane) * 8];
            half8 w1 = *(const half8*)&wch[(((s * 4 + ot) * 2 + 1) * 64 + lane) * 8];
            #pragma unroll
            for (int wt = 0; wt < 2; ++wt) {
                yacc[ot][wt] = __builtin_amdgcn_mfma_f32_16x16x32_f16(w0, bf[0][wt], yacc[ot][wt], 0, 0, 0);
                yacc[ot][wt] = __builtin_amdgcn_mfma_f32_16x16x32_f16(w1, bf[1][wt], yacc[ot][wt], 0, 0, 0);
            }
        }
    }

    // ---- epilogue: BN + residual, IN-PLACE into xs (each (o,t,w) owned by one lane) ----
    #pragma unroll
    for (int ot = 0; ot < 4; ++ot) {
        float4_t sc = *(const float4_t*)&bnsc[ot * 16 + quad * 4];   // 16B-aligned, L3-hot
        float4_t sh = *(const float4_t*)&bnsh[ot * 16 + quad * 4];
        #pragma unroll
        for (int i = 0; i < 4; ++i) {
            const int o = ot * 16 + quad * 4 + i;
            #pragma unroll
            for (int wt = 0; wt < 2; ++wt) {
                int w = wt * 16 + col;
                if (w < Vv) {
                    const int idx = o * 100 + wave * 25 + w;
                    float val = yacc[ot][wt][i] * sc[i] + sh[i] + xs[idx];
                    xs[idx] = fmaxf(val, 0.f);
                }
            }
        }
    }

    __syncthreads();   // all waves' results in xs before the streamed flush

    // ---- flush: 64 rows x 400 B contiguous (16B/lane float4, fully coalesced) ----
    float* ob = out + (size_t)n * Cc * Tt * Vv + t0 * Vv;
    for (int i = tid; i < 1600; i += 256) {
        int c = i / 25, q = i - c * 25;
        *(float4_t*)(ob + c * (Tt * Vv) + q * 4) = *(const float4_t*)&xs[i * 4];
    }
}

extern "C" void kernel_launch(void* const* d_in, const int* in_sizes, int n_in,
                              void* d_out, int out_size, void* d_ws, size_t ws_size,
                              hipStream_t stream) {
    const float* x     = (const float*)d_in[0];
    const float* A     = (const float*)d_in[1];
    const float* PA1   = (const float*)d_in[2];
    const float* PA2   = (const float*)d_in[3];
    const float* Wc    = (const float*)d_in[4];
    const float* bc    = (const float*)d_in[5];
    const float* gamma = (const float*)d_in[6];
    const float* beta  = (const float*)d_in[7];
    const float* rmean = (const float*)d_in[8];
    const float* rvar  = (const float*)d_in[9];
    float* out = (float*)d_out;

    // workspace layout (31,232 B): aeh | wch | bnsc | bnsh
    half_t* aeh = (half_t*)d_ws;                      // 3*2*64*8  = 3072 halfs
    half_t* wch = aeh + Ss * 2 * 64 * 8;              // 3*4*2*64*8 = 12288 halfs
    float* bnsc = (float*)(wch + Ss * 4 * 2 * 64 * 8);
    float* bnsh = bnsc + Cc;

    gcn_pre<<<dim3(1), 256, 0, stream>>>(A, PA1, PA2, Wc, bc, gamma, beta, rmean, rvar,
                                         aeh, wch, bnsc, bnsh);
    gcn_fused<<<dim3(Tt / 4, Nn), 256, 0, stream>>>(x, aeh, wch, bnsc, bnsh, out);
}